// Round 7
// baseline (360.087 us; speedup 1.0000x reference)
//
#include <hip/hip_runtime.h>
#include <math.h>

#define HID 128
#define HEADS 8
#define CDIM 16
#define NB1 256   // coarse histogram/scatter blocks

typedef short bf8 __attribute__((ext_vector_type(8)));
typedef float f32x4 __attribute__((ext_vector_type(4)));

__device__ __forceinline__ unsigned short f2bf(float f) {
    unsigned u = __float_as_uint(f);
    unsigned r = (u + 0x7fffu + ((u >> 16) & 1u)) >> 16;
    return (unsigned short)r;
}
__device__ __forceinline__ float bf2f(unsigned short u) {
    return __uint_as_float(((unsigned)u) << 16);
}

// ---- F1: blocks [0,NB1): coarse histogram; blocks [NB1,..): Wt transpose --
__global__ __launch_bounds__(256) void k_hist_tw(const float* __restrict__ W,
                                                 unsigned short* __restrict__ Wt,
                                                 const int* __restrict__ dst,
                                                 int* __restrict__ cntmat,
                                                 int E, int per, int nbkt) {
    __shared__ int h[256];
    int t = threadIdx.x;
    if (blockIdx.x >= NB1) {
        int idx = (blockIdx.x - NB1) * 256 + t; // 16384 total
        int j = idx >> 7, k = idx & 127;
        Wt[idx] = f2bf(W[k * HID + j]);
        return;
    }
    h[t] = 0;
    __syncthreads();
    int b0 = blockIdx.x * per;
    int b1 = min(b0 + per, E);
    for (int e = b0 + t; e < b1; e += 256)
        atomicAdd(&h[dst[e] >> 9], 1);
    __syncthreads();
    if (t < nbkt) cntmat[t * NB1 + blockIdx.x] = h[t];
}

// ---- generic exclusive scan over M ints (3 stages) ----------------------
__global__ __launch_bounds__(256) void kscanA(const int* __restrict__ in,
                                              int* __restrict__ tmp,
                                              int* __restrict__ bsum, int M) {
    __shared__ int lds[256];
    int t = threadIdx.x;
    int base = blockIdx.x * 1024 + t * 4;
    int v[4];
#pragma unroll
    for (int i = 0; i < 4; i++) {
        int idx = base + i;
        v[i] = (idx < M) ? in[idx] : 0;
    }
    int s = v[0] + v[1] + v[2] + v[3];
    lds[t] = s;
    __syncthreads();
    for (int off = 1; off < 256; off <<= 1) {
        int xv = (t >= off) ? lds[t - off] : 0;
        __syncthreads();
        lds[t] += xv;
        __syncthreads();
    }
    int run = (t > 0) ? lds[t - 1] : 0;
#pragma unroll
    for (int i = 0; i < 4; i++) {
        int idx = base + i;
        if (idx < M) tmp[idx] = run;
        run += v[i];
    }
    if (t == 255) bsum[blockIdx.x] = lds[255];
}

__global__ __launch_bounds__(128) void kscanB(const int* __restrict__ bsum,
                                              int* __restrict__ bscan, int nb,
                                              const float* __restrict__ w_edge,
                                              const float* __restrict__ att_edge,
                                              float* __restrict__ w_e) {
    __shared__ int lds[128];
    int t = threadIdx.x;
    if (t < HEADS) {
        float s = 0.f;
        for (int c = 0; c < CDIM; c++) s += w_edge[t * CDIM + c] * att_edge[t * CDIM + c];
        w_e[t] = s;
    }
    lds[t] = (t < nb) ? bsum[t] : 0;
    __syncthreads();
    for (int off = 1; off < 128; off <<= 1) {
        int xv = (t >= off) ? lds[t - off] : 0;
        __syncthreads();
        lds[t] += xv;
        __syncthreads();
    }
    bscan[t] = (t > 0) ? lds[t - 1] : 0;
}

__global__ __launch_bounds__(256) void kscanC(const int* __restrict__ tmp,
                                              const int* __restrict__ bscan,
                                              int* __restrict__ ofs, int M) {
    int i = blockIdx.x * 256 + threadIdx.x;
    if (i < M) ofs[i] = tmp[i] + bscan[i >> 10];
}

// ---- F2: blocks [0,SB): coarse scatter; blocks [SB,..): MFMA GEMM --------
__global__ __launch_bounds__(256) void k_scat_gemm(
        const int* __restrict__ src, const int* __restrict__ dst,
        const float* __restrict__ eattr, const int* __restrict__ ofs,
        int* __restrict__ d1, int2* __restrict__ erec1,
        int E, int per, int nbkt,
        const float* __restrict__ x, const unsigned short* __restrict__ Wt,
        const float* __restrict__ att_src, const float* __restrict__ att_dst,
        unsigned short* __restrict__ hbf, float* __restrict__ a_src,
        float* __restrict__ a_dst, int N) {
    __shared__ int cur[256];
    int tid = threadIdx.x;
    if (blockIdx.x < NB1) {
        // ---- coarse scatter ----
        if (tid < nbkt) cur[tid] = ofs[tid * NB1 + blockIdx.x];
        __syncthreads();
        int b0 = blockIdx.x * per;
        int b1 = min(b0 + per, E);
        for (int e = b0 + tid; e < b1; e += 256) {
            int d = dst[e];
            int pos = atomicAdd(&cur[d >> 9], 1);
            d1[pos] = d;
            erec1[pos] = make_int2(src[e], __float_as_int(eattr[e]));
        }
        return;
    }
    // ---- MFMA GEMM: wave computes 16 nodes x 128 cols ----
    int bid = blockIdx.x - NB1;
    int wv = tid >> 6, lane = tid & 63;
    int nloc = lane & 15, q = lane >> 4;
    int node = bid * 64 + wv * 16 + nloc;
    int nc = min(node, N - 1);
    const float* xp = x + (size_t)nc * HID + q * 8;
    const unsigned short* wp = Wt + nloc * HID + q * 8;
    f32x4 acc[8];
#pragma unroll
    for (int i = 0; i < 8; i++) acc[i] = (f32x4){0.f, 0.f, 0.f, 0.f};
#pragma unroll
    for (int ch = 0; ch < 4; ch++) {
        float4 xv0 = *(const float4*)(xp + ch * 32);
        float4 xv1 = *(const float4*)(xp + ch * 32 + 4);
        bf8 bfrag;
        bfrag[0] = (short)f2bf(xv0.x); bfrag[1] = (short)f2bf(xv0.y);
        bfrag[2] = (short)f2bf(xv0.z); bfrag[3] = (short)f2bf(xv0.w);
        bfrag[4] = (short)f2bf(xv1.x); bfrag[5] = (short)f2bf(xv1.y);
        bfrag[6] = (short)f2bf(xv1.z); bfrag[7] = (short)f2bf(xv1.w);
#pragma unroll
        for (int jt = 0; jt < 8; jt++) {
            bf8 afrag = *(const bf8*)(wp + (size_t)jt * 16 * HID + ch * 32);
            acc[jt] = __builtin_amdgcn_mfma_f32_16x16x32_bf16(afrag, bfrag, acc[jt], 0, 0, 0);
        }
    }
    bool ok = node < N;
    size_t hb = (size_t)nc * HID;
#pragma unroll
    for (int jt = 0; jt < 8; jt++) {
        int j0 = jt * 16 + q * 4;
        float4 as4 = *(const float4*)(att_src + j0);
        float4 ad4 = *(const float4*)(att_dst + j0);
        f32x4 a = acc[jt];
        float ps = a[0] * as4.x + a[1] * as4.y + a[2] * as4.z + a[3] * as4.w;
        float pd = a[0] * ad4.x + a[1] * ad4.y + a[2] * ad4.z + a[3] * ad4.w;
        ps += __shfl_xor(ps, 16, 64); ps += __shfl_xor(ps, 32, 64);
        pd += __shfl_xor(pd, 16, 64); pd += __shfl_xor(pd, 32, 64);
        if (ok) {
            ushort4 hv;
            hv.x = f2bf(a[0]); hv.y = f2bf(a[1]); hv.z = f2bf(a[2]); hv.w = f2bf(a[3]);
            *(ushort4*)(hbf + hb + j0) = hv;
            if (q == 0) {
                a_src[(size_t)node * 8 + jt] = ps;
                a_dst[(size_t)node * 8 + jt] = pd;
            }
        }
    }
}

// ---- S3: fine bin within bucket -> row_ptr + erec (LDS only) ------------
__global__ __launch_bounds__(256) void k_bin(const int* __restrict__ ofs,
                                             const int* __restrict__ d1,
                                             const int2* __restrict__ erec1,
                                             int* __restrict__ row_ptr,
                                             int2* __restrict__ erec,
                                             int N, int E, int nbkt) {
    __shared__ int h2[512];
    __shared__ int s2[256];
    __shared__ int cur2[512];
    int b = blockIdx.x, t = threadIdx.x;
    int base = ofs[b * NB1];
    int end = (b + 1 < nbkt) ? ofs[(b + 1) * NB1] : E;
    h2[t] = 0; h2[t + 256] = 0;
    __syncthreads();
    for (int e = base + t; e < end; e += 256)
        atomicAdd(&h2[d1[e] & 511], 1);
    __syncthreads();
    int a0 = h2[2 * t], a1 = h2[2 * t + 1];
    s2[t] = a0 + a1;
    __syncthreads();
    for (int off = 1; off < 256; off <<= 1) {
        int v = (t >= off) ? s2[t - off] : 0;
        __syncthreads();
        s2[t] += v;
        __syncthreads();
    }
    int ex = (t > 0) ? s2[t - 1] : 0;
    int p0 = base + ex;
    int p1 = p0 + a0;
    int ng = b * 512 + 2 * t;
    if (ng <= N) row_ptr[ng] = p0;
    if (ng + 1 <= N) row_ptr[ng + 1] = p1;
    cur2[2 * t] = p0;
    cur2[2 * t + 1] = p1;
    __syncthreads();
    for (int e = base + t; e < end; e += 256) {
        int d = d1[e];
        int pos = atomicAdd(&cur2[d & 511], 1);
        erec[pos] = erec1[e];
    }
}

// ---- K6: per-node fused attn+aggregate+selfloop+LN+ReLU -----------------
__global__ __launch_bounds__(64) void k_node(const int* __restrict__ row_ptr,
                                             const int2* __restrict__ erec,
                                             const float* __restrict__ a_src,
                                             const float* __restrict__ a_dst,
                                             const float* __restrict__ w_e,
                                             const unsigned short* __restrict__ hbf,
                                             const float* __restrict__ x,
                                             const float* __restrict__ bias,
                                             const float* __restrict__ gamma,
                                             const float* __restrict__ beta,
                                             float* __restrict__ out, int N) {
    int n = blockIdx.x;
    int lane = threadIdx.x;
    int r0 = row_ptr[n], r1 = row_ptr[n + 1];
    __shared__ float lex[64][9]; // stride 9 (odd) -> conflict-free
    __shared__ int lsrc[64];     // byte offsets into hbf
    float ad[8], we[8];
#pragma unroll
    for (int q = 0; q < 8; q++) {
        ad[q] = a_dst[(size_t)n * 8 + q];
        we[q] = w_e[q];
    }
    float acc0 = 0.f, acc1 = 0.f;
    float wsum = 0.f;  // per-lane: sum of exp-weights for OWN head
    float suma = 0.f;  // per-lane partial of sum(eattr)
    int head = lane >> 3;

    for (int base = r0; base < r1; base += 64) {
        int e = base + lane;
        if (e < r1) {
            int2 rec = erec[e];
            int s = rec.x;
            float a = __int_as_float(rec.y);
            suma += a;
            lsrc[lane] = s << 8; // s * HID * sizeof(bf16)
            const float4* asp = (const float4*)(a_src + (size_t)s * 8);
            float4 s0 = asp[0], s1 = asp[1];
            float al[8] = {s0.x, s0.y, s0.z, s0.w, s1.x, s1.y, s1.z, s1.w};
#pragma unroll
            for (int q = 0; q < 8; q++) {
                float v = al[q] + ad[q] + a * we[q];
                v = v > 0.f ? v : 0.2f * v;
                lex[lane][q] = __expf(v);
            }
        }
        __syncthreads();
        int cntc = min(64, r1 - base);
        for (int kk = 0; kk < cntc; kk++) {
            int soff = __builtin_amdgcn_readfirstlane(lsrc[kk]);
            const unsigned* hp = (const unsigned*)((const char*)hbf + soff);
            unsigned u = hp[lane];                 // channels (2*lane, 2*lane+1)
            float w = lex[kk][head];
            wsum += w;
            acc0 = fmaf(w, __uint_as_float(u << 16), acc0);
            acc1 = fmaf(w, __uint_as_float(u & 0xffff0000u), acc1);
        }
        __syncthreads();
    }
#pragma unroll
    for (int off = 32; off; off >>= 1) suma += __shfl_xor(suma, off, 64);

    // ---- self-loop: edge_attr = mean of incoming eattr, src = n ----
    int deg = r1 - r0;
    float la = suma / fmaxf((float)deg, 1.0f);
    float vs = a_src[(size_t)n * 8 + head] + ad[head] + la * we[head];
    vs = vs > 0.f ? vs : 0.2f * vs;
    float exs = __expf(vs);
    size_t bx = (size_t)n * HID;
    unsigned us = ((const unsigned*)((const char*)hbf + ((size_t)n << 8)))[lane];
    acc0 = fmaf(exs, __uint_as_float(us << 16), acc0);
    acc1 = fmaf(exs, __uint_as_float(us & 0xffff0000u), acc1);
    float inv = 1.f / (wsum + exs + 1e-16f);

    float2 xv = *(const float2*)(x + bx + 2 * lane);
    float2 bv = *(const float2*)(bias + 2 * lane);
    float y0 = acc0 * inv + bv.x + xv.x;
    float y1 = acc1 * inv + bv.y + xv.y;
    float ss = y0 + y1, sq = y0 * y0 + y1 * y1;
#pragma unroll
    for (int off = 32; off; off >>= 1) {
        ss += __shfl_xor(ss, off, 64);
        sq += __shfl_xor(sq, off, 64);
    }
    float mu = ss * (1.f / 128.f);
    float var = sq * (1.f / 128.f) - mu * mu;
    float r = rsqrtf(fmaxf(var, 0.f) + 1e-5f);
    float2 gv = *(const float2*)(gamma + 2 * lane);
    float2 tv = *(const float2*)(beta + 2 * lane);
    float o0 = (y0 - mu) * r * gv.x + tv.x;
    float o1 = (y1 - mu) * r * gv.y + tv.y;
    float2 ov = make_float2(fmaxf(o0, 0.f), fmaxf(o1, 0.f));
    *(float2*)(out + bx + 2 * lane) = ov;
}

extern "C" void kernel_launch(void* const* d_in, const int* in_sizes, int n_in,
                              void* d_out, int out_size, void* d_ws, size_t ws_size,
                              hipStream_t stream) {
    const float* x        = (const float*)d_in[0];
    const int*   ei       = (const int*)d_in[1];
    const float* eattr    = (const float*)d_in[2];
    const float* W        = (const float*)d_in[3];
    const float* att_src  = (const float*)d_in[4];
    const float* att_dst  = (const float*)d_in[5];
    const float* w_edge   = (const float*)d_in[6];
    const float* att_edge = (const float*)d_in[7];
    const float* bias     = (const float*)d_in[8];
    const float* gamma    = (const float*)d_in[9];
    const float* beta     = (const float*)d_in[10];

    int N = in_sizes[0] / HID;
    int E = in_sizes[2];
    const int* src = ei;
    const int* dst = ei + E;
    float* out = (float*)d_out;

    int nbkt = (N + 511) >> 9;          // 196
    int M = nbkt * NB1;                 // 50176
    int per = (E + NB1 - 1) / NB1;      // 6250

    char* ws = (char*)d_ws;
    size_t off = 0;
    auto alloc = [&](size_t bytes) { char* p = ws + off; off += (bytes + 255) & ~255ull; return p; };
    unsigned short* hbf = (unsigned short*)alloc((size_t)N * HID * 2);
    unsigned short* Wt  = (unsigned short*)alloc((size_t)HID * HID * 2);
    float* a_src   = (float*)alloc((size_t)N * 8 * 4);
    float* a_dst   = (float*)alloc((size_t)N * 8 * 4);
    int2*  erec    = (int2*) alloc((size_t)E * 8);
    int2*  erec1   = (int2*) alloc((size_t)E * 8);
    int*   d1      = (int*)  alloc((size_t)E * 4);
    int*   cntmat  = (int*)  alloc((size_t)M * 4);
    int*   stmp    = (int*)  alloc((size_t)M * 4);
    int*   ofs     = (int*)  alloc((size_t)M * 4);
    int*   bsum    = (int*)  alloc(128 * 4);
    int*   bscan   = (int*)  alloc(128 * 4);
    int*   row_ptr = (int*)  alloc((size_t)(N + 1) * 4);
    float* w_e     = (float*)alloc(8 * 4);

    int nbA = (M + 1023) / 1024;
    int GB = (N + 63) / 64;

    k_hist_tw<<<NB1 + 64, 256, 0, stream>>>(W, Wt, dst, cntmat, E, per, nbkt);
    kscanA<<<nbA, 256, 0, stream>>>(cntmat, stmp, bsum, M);
    kscanB<<<1, 128, 0, stream>>>(bsum, bscan, nbA, w_edge, att_edge, w_e);
    kscanC<<<(M + 255) / 256, 256, 0, stream>>>(stmp, bscan, ofs, M);
    k_scat_gemm<<<NB1 + GB, 256, 0, stream>>>(src, dst, eattr, ofs, d1, erec1,
                                              E, per, nbkt,
                                              x, Wt, att_src, att_dst, hbf,
                                              a_src, a_dst, N);
    k_bin<<<nbkt, 256, 0, stream>>>(ofs, d1, erec1, row_ptr, erec, N, E, nbkt);
    k_node<<<N, 64, 0, stream>>>(row_ptr, erec, a_src, a_dst, w_e, hbf, x,
                                 bias, gamma, beta, out, N);
}